// Round 1
// baseline (469.898 us; speedup 1.0000x reference)
//
#include <hip/hip_runtime.h>
#include <hip/hip_bf16.h>

#define PATCH 4
#define EMBED 96
#define HIN 512
#define WIN 512
#define HP 128
#define WP 128
#define BATCH 8
#define CHAN 8   // 3 rgb + 4 hs + 1 dem

// One block (256 threads) handles one (b, c, hp_pair): 2 hp rows x 128 wp.
// Each thread: load its 4x4 patch as 4 float4 (coalesced), loop over 96 embed
// dims with uniform (scalar-cached) weight loads, one coalesced dword store per e.
__global__ __launch_bounds__(256, 4)
void patch_embed_kernel(const float* __restrict__ rgb,
                        const float* __restrict__ hs,
                        const float* __restrict__ dem,
                        const float* __restrict__ W,
                        const float* __restrict__ bias,
                        float* __restrict__ out) {
    const int blk = blockIdx.x;          // 0 .. 8*8*64-1
    const int hp2 = blk & 63;            // hp pair index (64 pairs of rows)
    const int bc  = blk >> 6;            // 0..63
    const int b   = bc >> 3;
    const int c   = bc & 7;

    const int tid = threadIdx.x;
    const int hp  = hp2 * 2 + (tid >> 7);   // 2 rows per block
    const int wp  = tid & 127;

    // channel -> source plane (concat order: rgb[0..2], hs[3..6], dem[7])
    const float* src;
    if (c < 3)      src = rgb + (size_t)(b * 3 + c)       * (HIN * WIN);
    else if (c < 7) src = hs  + (size_t)(b * 4 + (c - 3)) * (HIN * WIN);
    else            src = dem + (size_t)b                 * (HIN * WIN);

    const float* row0 = src + (size_t)(hp * PATCH) * WIN + wp * PATCH;
    const float4 p0 = *(const float4*)(row0);
    const float4 p1 = *(const float4*)(row0 + WIN);
    const float4 p2 = *(const float4*)(row0 + 2 * WIN);
    const float4 p3 = *(const float4*)(row0 + 3 * WIN);

    // out[b, c*96+e, hp, wp]; stride per e step = HP*WP
    float* outp = out + (((size_t)(b * CHAN * EMBED + c * EMBED) * HP + hp) * WP + wp);

    #pragma unroll 4
    for (int e = 0; e < EMBED; ++e) {
        const float4 w0 = *(const float4*)(W + e * 16);
        const float4 w1 = *(const float4*)(W + e * 16 + 4);
        const float4 w2 = *(const float4*)(W + e * 16 + 8);
        const float4 w3 = *(const float4*)(W + e * 16 + 12);
        float acc = bias[e];
        acc = fmaf(p0.x, w0.x, acc); acc = fmaf(p0.y, w0.y, acc);
        acc = fmaf(p0.z, w0.z, acc); acc = fmaf(p0.w, w0.w, acc);
        acc = fmaf(p1.x, w1.x, acc); acc = fmaf(p1.y, w1.y, acc);
        acc = fmaf(p1.z, w1.z, acc); acc = fmaf(p1.w, w1.w, acc);
        acc = fmaf(p2.x, w2.x, acc); acc = fmaf(p2.y, w2.y, acc);
        acc = fmaf(p2.z, w2.z, acc); acc = fmaf(p2.w, w2.w, acc);
        acc = fmaf(p3.x, w3.x, acc); acc = fmaf(p3.y, w3.y, acc);
        acc = fmaf(p3.z, w3.z, acc); acc = fmaf(p3.w, w3.w, acc);
        outp[(size_t)e * (HP * WP)] = acc;
    }
}

extern "C" void kernel_launch(void* const* d_in, const int* in_sizes, int n_in,
                              void* d_out, int out_size, void* d_ws, size_t ws_size,
                              hipStream_t stream) {
    const float* rgb  = (const float*)d_in[0];
    const float* hs   = (const float*)d_in[1];
    const float* dem  = (const float*)d_in[2];
    const float* W    = (const float*)d_in[3];
    const float* bias = (const float*)d_in[4];
    float* out = (float*)d_out;

    const int grid = BATCH * CHAN * (HP / 2);   // 8*8*64 = 4096 blocks
    patch_embed_kernel<<<grid, 256, 0, stream>>>(rgb, hs, dem, W, bias, out);
}